// Round 8
// baseline (212.897 us; speedup 1.0000x reference)
//
#include <hip/hip_runtime.h>

// ---------------------------------------------------------------------------
// PEPS 4x5, D=4, P=2, depth-5 gate sweeps, 64-point gather.
// ONE persistent kernel (plain launch), 13 fence-free tree barriers:
//   P1 cols -> P2 {M34T || M01} -> P3 t012 -> P4 psi0 -> 5x(G-P1, G-P2).
//
// COHERENCE PROTOCOL (r6 lesson): harness re-poisons ws with cached stores
// whose clean copies linger in L2; sc0 sc1 stores do NOT update them. So
// EVERY ws access is coherent (stores sc0 sc1 asm; loads sc0 sc1 asm x4 or
// __hip_atomic_load AGENT). Cached reads ONLY for true inputs (peps/x/gate).
//
// r8: setup GEMM-lets restructured for REUSE (r7 streamed ~400MB coherent;
// now ~40MB): M01 16 blocks/col1-once; t012 128 blocks/col2 x8; psi0 128
// blocks/m34t x128. Shared coh_gemm: 8+8 double-buffered dwordx4 loads,
// counted vmcnt(8), sched_barrier(0) after every wait (rule #18).
// Gate layout: psi idx = c3<<16 | c4<<12 | c0<<8 | c1<<4 | c2.
// ---------------------------------------------------------------------------

#define PAD(i) ((i) + (((i) >> 4) << 2))   // +4 floats per 16 -> LDS bank spread
#define PIDX(i,j,p,u,d,l,r) (((((((i)*5+(j))*2+(p))*4+(u))*4+(d))*4+(l))*4+(r))

typedef float v4f __attribute__((ext_vector_type(4)));

// workspace float offsets
static constexpr int COL0  = 0;                    // [16][256]
static constexpr int COL1  = 4096;                 // [16][256][256]
static constexpr int COL2  = COL1 + 1048576;
static constexpr int COL3  = COL2 + 1048576;
static constexpr int COL4  = COL3 + 1048576;       // [16][256]
static constexpr int M01TO = COL4 + 4096;          // [c01=256][R2=256]
static constexpr int M34TO = M01TO + 65536;        // [L3=256][c34=256]
static constexpr int T12TO = M34TO + 65536;        // [c2=16][c01=256][R3=256]
static constexpr int PSIO  = T12TO + 1048576;      // [2^20] gate layout
static constexpr int CNTO  = PSIO + 1048576;       // barrier tree: 1088 ints

// ---------------- coherent-point access ------------------------------------
__device__ __forceinline__ float agl(const float* p) {      // coherent load
  return __hip_atomic_load(p, __ATOMIC_RELAXED, __HIP_MEMORY_SCOPE_AGENT);
}
__device__ __forceinline__ void cohload1(const float* p, v4f& a) {  // no wait!
  asm volatile("global_load_dwordx4 %0, %1, off sc0 sc1"
               : "=&v"(a) : "v"(p) : "memory");
}
__device__ __forceinline__ void cohload2(const float* p0, const float* p1,
                                         v4f& a, v4f& b) {
  asm volatile(
      "global_load_dwordx4 %0, %2, off sc0 sc1\n\t"
      "global_load_dwordx4 %1, %3, off sc0 sc1\n\t"
      "s_waitcnt vmcnt(0)"
      : "=&v"(a), "=&v"(b)
      : "v"(p0), "v"(p1)
      : "memory");
}
__device__ __forceinline__ void cohstore(float* p, v4f v) {
  asm volatile("global_store_dwordx4 %0, %1, off sc0 sc1"
               :
               : "v"(p), "v"(v)
               : "memory");
}
__device__ __forceinline__ void cohstore1(float* p, float v) {
  asm volatile("global_store_dword %0, %1, off sc0 sc1"
               :
               : "v"(p), "v"(v)
               : "memory");
}
__device__ __forceinline__ void vmdrain() {
  asm volatile("s_waitcnt vmcnt(0)" ::: "memory");
}
// waits with rule-#18 fence (register-only FMA must not hoist past the wait)
__device__ __forceinline__ void vmw8() {
  asm volatile("s_waitcnt vmcnt(8)" ::: "memory");
  __builtin_amdgcn_sched_barrier(0);
}
__device__ __forceinline__ void vmw0() {
  asm volatile("s_waitcnt vmcnt(0)" ::: "memory");
  __builtin_amdgcn_sched_barrier(0);
}

// ---------------- two-level fence-free grid barrier ------------------------
__device__ __forceinline__ void gridbar(int* cnts, int gen) {
  vmdrain();        // asm stores untracked by compiler: drain manually
  __syncthreads();  // all waves' stores completed at coherent point
  if (threadIdx.x == 0) {
    int* gc = cnts + (blockIdx.x >> 4) * 64;
    int* root = cnts + 1024;
    int prev = __hip_atomic_fetch_add(gc, 1, __ATOMIC_RELAXED,
                                      __HIP_MEMORY_SCOPE_AGENT);
    if ((prev & 15) == 15)
      __hip_atomic_fetch_add(root, 1, __ATOMIC_RELAXED,
                             __HIP_MEMORY_SCOPE_AGENT);
    while (__hip_atomic_load(root, __ATOMIC_RELAXED,
                             __HIP_MEMORY_SCOPE_AGENT) < gen * 16) {
      __builtin_amdgcn_s_sleep(2);
    }
  }
  __syncthreads();
}

// ---------------- pipelined coherent GEMM inner loop -----------------------
// acc[r][0..3] += sum_R A[r][R] * B[R][cg*4 .. cg*4+3], R = 0..255.
// Bb = &B[0][cg*4] (row stride 256); Ar = &A_lds[0] (row stride 256, LDS,
// wave-uniform reads). 8+8 double-buffer of dwordx4 coherent loads.
__device__ __forceinline__ void coh_gemm(const float* Bb, const float* Ar,
                                         v4f acc[4]) {
  v4f pa0, pa1, pa2, pa3, pa4, pa5, pa6, pa7;
  v4f pb0, pb1, pb2, pb3, pb4, pb5, pb6, pb7;
#define ISSUE8(buf, base)                                                      \
  cohload1(Bb + ((base) + 0) * 256, buf##0);                                   \
  cohload1(Bb + ((base) + 1) * 256, buf##1);                                   \
  cohload1(Bb + ((base) + 2) * 256, buf##2);                                   \
  cohload1(Bb + ((base) + 3) * 256, buf##3);                                   \
  cohload1(Bb + ((base) + 4) * 256, buf##4);                                   \
  cohload1(Bb + ((base) + 5) * 256, buf##5);                                   \
  cohload1(Bb + ((base) + 6) * 256, buf##6);                                   \
  cohload1(Bb + ((base) + 7) * 256, buf##7)
#define FMA8(buf, base)                                                        \
  {                                                                            \
    _Pragma("unroll") for (int r = 0; r < 4; ++r) {                            \
      acc[r] += buf##0 * Ar[r * 256 + (base) + 0];                             \
      acc[r] += buf##1 * Ar[r * 256 + (base) + 1];                             \
      acc[r] += buf##2 * Ar[r * 256 + (base) + 2];                             \
      acc[r] += buf##3 * Ar[r * 256 + (base) + 3];                             \
      acc[r] += buf##4 * Ar[r * 256 + (base) + 4];                             \
      acc[r] += buf##5 * Ar[r * 256 + (base) + 5];                             \
      acc[r] += buf##6 * Ar[r * 256 + (base) + 6];                             \
      acc[r] += buf##7 * Ar[r * 256 + (base) + 7];                             \
    }                                                                          \
  }
  ISSUE8(pa, 0);
#pragma unroll
  for (int cp = 0; cp < 16; ++cp) {
    ISSUE8(pb, cp * 16 + 8);
    vmw8();                       // pa ready (8 pb outstanding)
    FMA8(pa, cp * 16);
    if (cp < 15) {
      ISSUE8(pa, cp * 16 + 16);
      vmw8();                     // pb ready (8 pa outstanding)
    } else {
      vmw0();
    }
    FMA8(pb, cp * 16 + 8);
  }
#undef ISSUE8
#undef FMA8
}

// stage 8192 consecutive floats gsrc -> lds (512 threads, coherent x4)
__device__ __forceinline__ void stage8k(const float* gsrc, float* lds, int t) {
  v4f v0, v1, v2, v3;
  cohload1(gsrc + (0 * 512 + t) * 4, v0);
  cohload1(gsrc + (1 * 512 + t) * 4, v1);
  cohload1(gsrc + (2 * 512 + t) * 4, v2);
  cohload1(gsrc + (3 * 512 + t) * 4, v3);
  vmw0();
  *(v4f*)&lds[(0 * 512 + t) * 4] = v0;
  *(v4f*)&lds[(1 * 512 + t) * 4] = v1;
  *(v4f*)&lds[(2 * 512 + t) * 4] = v2;
  *(v4f*)&lds[(3 * 512 + t) * 4] = v3;
}

// ---------------- register-level 2-qubit gate ------------------------------
template <int NB, int HI, int LO>
__device__ __forceinline__ void gate2(float* x, const float* __restrict__ g) {
  constexpr int H = 1 << HI, L = 1 << LO, N = 1 << NB;
#pragma unroll
  for (int o = 0; o < N; ++o) {
    if (o & (H | L)) continue;
    float v0 = x[o], v1 = x[o + L], v2 = x[o + H], v3 = x[o + H + L];
    x[o]         = g[0]  * v0 + g[1]  * v1 + g[2]  * v2 + g[3]  * v3;
    x[o + L]     = g[4]  * v0 + g[5]  * v1 + g[6]  * v2 + g[7]  * v3;
    x[o + H]     = g[8]  * v0 + g[9]  * v1 + g[10] * v2 + g[11] * v3;
    x[o + H + L] = g[12] * v0 + g[13] * v1 + g[14] * v2 + g[15] * v3;
  }
}

template <int ST>
__device__ __forceinline__ void vxf(float* s, const float* __restrict__ g, int b) {
  float x[16];
#pragma unroll
  for (int m = 0; m < 16; ++m) x[m] = s[PAD(b + m * ST)];
  gate2<4, 3, 2>(x, g);
  gate2<4, 2, 1>(x, g);
  gate2<4, 1, 0>(x, g);
#pragma unroll
  for (int m = 0; m < 16; ++m) s[PAD(b + m * ST)] = x[m];
}

template <int B2, int B1, int B0>
__device__ __forceinline__ void bondpair(float* s, const float* __restrict__ g,
                                         int t) {
  constexpr int MASK = (1 << B2) | (1 << B1) | (1 << B0);
  int b = 0, rem = t;
#pragma unroll
  for (int p = 0; p < 12; ++p) {
    if (!((MASK >> p) & 1)) {
      b |= (rem & 1) << p;
      rem >>= 1;
    }
  }
  float x[8];
#pragma unroll
  for (int m = 0; m < 8; ++m) {
    int off = ((m >> 2) & 1) * (1 << B2) + ((m >> 1) & 1) * (1 << B1) +
              (m & 1) * (1 << B0);
    x[m] = s[PAD(b + off)];
  }
  gate2<3, 2, 1>(x, g);  // bond (B2, B1)
  gate2<3, 1, 0>(x, g);  // bond (B1, B0)
#pragma unroll
  for (int m = 0; m < 8; ++m) {
    int off = ((m >> 2) & 1) * (1 << B2) + ((m >> 1) & 1) * (1 << B1) +
              (m & 1) * (1 << B0);
    s[PAD(b + off)] = x[m];
  }
}

// ---------------------------------------------------------------------------
// Grid 256 x 512, plain launch. LDS 12320 floats (49.3KB) -> co-resident.
// ---------------------------------------------------------------------------
__global__ __launch_bounds__(512) void k_all(const float* __restrict__ peps,
                                             const int* __restrict__ x,
                                             const float* __restrict__ gate,
                                             float* __restrict__ ws,
                                             float* __restrict__ out,
                                             int* __restrict__ cnt) {
  __shared__ float sm[12320];
  const int t = threadIdx.x;   // 0..511
  const int b = blockIdx.x;    // 0..255
  const int cg = t & 63;       // gemm column group (4 cols each)
  float* psi = ws + PSIO;
  int gen = 0;

  // ===================== phase 1: column tensors ===========================
  if (b < 192) {
    float* p01 = sm;
    float* p23 = sm + 4096;
    int col = 1 + (b >> 6);
    int pb = b & 63;
#pragma unroll
    for (int k = 0; k < 8; ++k) {
      int e = k * 512 + t;
      int r12 = e & 15, l12 = (e >> 4) & 15, d2 = (e >> 8) & 3, p = e >> 10;
      int l1 = l12 >> 2, l2 = l12 & 3, r1 = r12 >> 2, r2 = r12 & 3;
      float s01 = 0.f, s23 = 0.f;
#pragma unroll
      for (int d = 0; d < 4; ++d) {
        s01 += peps[PIDX(0, col, (p >> 1), 0, d, l1, r1)] *
               peps[PIDX(1, col, (p & 1), d, d2, l2, r2)];
        s23 += peps[PIDX(2, col, (p >> 1), d2, d, l1, r1)] *
               peps[PIDX(3, col, (p & 1), d, 0, l2, r2)];
      }
      p01[e] = s01;
      p23[e] = s23;
    }
    __syncthreads();
    const int coloffs[3] = {COL1, COL2, COL3};
    float* outc = ws + coloffs[col - 1];
#pragma unroll
    for (int pp = 0; pp < 2; ++pp) {
      int part = pb * 2 + pp;
#pragma unroll
      for (int k = 0; k < 4; ++k) {
        int eq = part * 8192 + (k * 512 + t) * 4;
        int r34b = eq & 15;
        int r12 = (eq >> 4) & 15, l34 = (eq >> 8) & 15, l12 = (eq >> 12) & 15;
        int p = eq >> 16;
        int pa = p >> 2, pbv = p & 3;
        v4f acc = {0.f, 0.f, 0.f, 0.f};
#pragma unroll
        for (int d2 = 0; d2 < 4; ++d2) {
          float a01 = p01[((((pa * 4 + d2) << 4) | l12) << 4) | r12];
          const float4 b4 =
              *(const float4*)&p23[((((pbv * 4 + d2) << 4) | l34) << 4) | r34b];
          acc.x += a01 * b4.x;
          acc.y += a01 * b4.y;
          acc.z += a01 * b4.z;
          acc.w += a01 * b4.w;
        }
        cohstore(&outc[eq], acc);
      }
    }
  } else if (b < 194) {
    float* p01 = sm;
    float* p23 = sm + 4096;
    int col = (b == 192) ? 0 : 4;
    const int lsh = (col == 0) ? 0 : 2;
    const int rsh = (col == 4) ? 0 : 2;
    const int ldim = 1 << lsh, rdim = 1 << rsh;
    const int LLB = 2 * lsh, RRB = 2 * rsh;
    const int LL = 1 << LLB, RR = 1 << RRB;
    int n12 = (LL * RR) << 4;
    for (int e = t; e < n12; e += 512) {
      int r12 = e & (RR - 1);
      int l12 = (e >> RRB) & (LL - 1);
      int d2 = (e >> (RRB + LLB)) & 3;
      int p = e >> (RRB + LLB + 2);
      int l1 = l12 >> lsh, l2 = l12 & (ldim - 1);
      int r1 = r12 >> rsh, r2 = r12 & (rdim - 1);
      float s01 = 0.f, s23 = 0.f;
      for (int d = 0; d < 4; ++d) {
        s01 += peps[PIDX(0, col, (p >> 1), 0, d, l1, r1)] *
               peps[PIDX(1, col, (p & 1), d, d2, l2, r2)];
        s23 += peps[PIDX(2, col, (p >> 1), d2, d, l1, r1)] *
               peps[PIDX(3, col, (p & 1), d, 0, l2, r2)];
      }
      p01[e] = s01;
      p23[e] = s23;
    }
    __syncthreads();
    const int LB = 2 * LLB, RB = 2 * RRB;
    int total = 16 << (LB + RB);
    float* outc = ws + ((col == 0) ? COL0 : COL4);
    for (int e = t; e < total; e += 512) {
      int r = e & ((1 << RB) - 1);
      int l = (e >> RB) & ((1 << LB) - 1);
      int p = e >> (RB + LB);
      int r34 = r & (RR - 1), r12 = r >> RRB;
      int l34 = l & (LL - 1), l12 = l >> LLB;
      int pa = p >> 2, pbv = p & 3;
      float sacc = 0.f;
      for (int d2 = 0; d2 < 4; ++d2) {
        sacc += p01[((((pa * 4 + d2) << LLB) | l12) << RRB) | r12] *
                p23[((((pbv * 4 + d2) << LLB) | l34) << RRB) | r34];
      }
      cohstore1(&outc[e], sacc);
    }
  }
  gridbar(cnt, ++gen);

  // ===== phase 2: M34T (t<256, block=L3)  ||  M01 (t>=256, blocks 0..15) ===
  {
    float* c3buf = sm;            // [4112]
    float* c4buf = sm + 4112;     // [4112]
    float* col0l = sm + 8224;     // [4096]
    const float* col3 = ws + COL3;
    const float* col4 = ws + COL4;
    const float* col0g = ws + COL0;
    const int L3 = b;
    if (t < 256) {
      float v3[16], v4[16];
#pragma unroll
      for (int k = 0; k < 16; ++k) {
        v4[k] = agl(&col4[k * 256 + t]);
        v3[k] = agl(&col3[k * 65536 + L3 * 256 + t]);
      }
#pragma unroll
      for (int k = 0; k < 16; ++k) {
        c4buf[k * 257 + t] = v4[k];
        c3buf[k * 257 + t] = v3[k];
      }
    } else if (b < 16) {
      int tt = t - 256;
#pragma unroll
      for (int k = 0; k < 16; ++k) col0l[k * 256 + tt] = agl(&col0g[k * 256 + tt]);
    }
    __syncthreads();
    if (t < 256) {
      int c3 = t >> 4, c4 = t & 15;
      float acc = 0.f;
      for (int B = 0; B < 256; ++B)
        acc += c3buf[c3 * 257 + B] * c4buf[c4 * 257 + B];
      cohstore1(&(ws + M34TO)[L3 * 256 + t], acc);
    } else if (b < 16) {
      // M01[c01][R2] = sum_R1 col0[c0][R1] * col1[c1][R1][R2]; block = c1.
      int rg = (t >> 6) & 3;  // c0 group (4 rows each)
      v4f acc[4] = {};
      coh_gemm(ws + COL1 + b * 65536 + cg * 4, &col0l[rg * 4 * 256], acc);
      float* m01p = ws + M01TO;
#pragma unroll
      for (int r = 0; r < 4; ++r)
        cohstore(&m01p[((rg * 4 + r) * 16 + b) * 256 + cg * 4], acc[r]);
    }
  }
  gridbar(cnt, ++gen);

  // ======= phase 3: T012[c2][c01][R3] = M01 x Col2 (blocks 0..127) =========
  if (b < 128) {
    float* A = sm;               // [32 rows][256 R2] = 8192
    int c2 = b & 15, hb = b >> 4;  // 8 row-tiles of 32 c01-rows
    stage8k(ws + M01TO + hb * 8192, A, t);
    __syncthreads();
    int rg = t >> 6;             // 8 row groups x 4 rows
    v4f acc[4] = {};
    coh_gemm(ws + COL2 + c2 * 65536 + cg * 4, &A[rg * 4 * 256], acc);
    float* t012p = ws + T12TO;
#pragma unroll
    for (int r = 0; r < 4; ++r)
      cohstore(&t012p[c2 * 65536 + (hb * 32 + rg * 4 + r) * 256 + cg * 4],
               acc[r]);
  }
  gridbar(cnt, ++gen);

  // ==== phase 4: psi = T012 x M34T, gate layout (blocks 0..127, tg pair) ===
  if (b < 128) {
    float* A = sm;               // [32 rows = tgl*16+c2][256 L3] = 8192
    float* S = sm;               // aliases A (A dead after gemm)
    {  // stage A: A[ri][col] = t012[ri&15][2b + (ri>>4)][col]
      v4f v0, v1, v2, v3;
      const float* t012p = ws + T12TO;
      int f0 = (0 * 512 + t) * 4, f1 = (1 * 512 + t) * 4;
      int f2 = (2 * 512 + t) * 4, f3 = (3 * 512 + t) * 4;
      cohload1(t012p + (((f0 >> 8) & 15) * 65536 + (2 * b + (f0 >> 12)) * 256 +
                        (f0 & 255)), v0);
      cohload1(t012p + (((f1 >> 8) & 15) * 65536 + (2 * b + (f1 >> 12)) * 256 +
                        (f1 & 255)), v1);
      cohload1(t012p + (((f2 >> 8) & 15) * 65536 + (2 * b + (f2 >> 12)) * 256 +
                        (f2 & 255)), v2);
      cohload1(t012p + (((f3 >> 8) & 15) * 65536 + (2 * b + (f3 >> 12)) * 256 +
                        (f3 & 255)), v3);
      vmw0();
      *(v4f*)&A[f0] = v0;
      *(v4f*)&A[f1] = v1;
      *(v4f*)&A[f2] = v2;
      *(v4f*)&A[f3] = v3;
    }
    __syncthreads();
    int rg = t >> 6;
    v4f acc[4] = {};
    coh_gemm(ws + M34TO + cg * 4, &A[rg * 4 * 256], acc);
    __syncthreads();             // A reads done; S may overwrite
#pragma unroll
    for (int r = 0; r < 4; ++r) {
      int ri = rg * 4 + r;
      int sb = (ri >> 4) * 4112 + (ri & 15) * 257 + cg * 4;
      S[sb + 0] = acc[r].x;
      S[sb + 1] = acc[r].y;
      S[sb + 2] = acc[r].z;
      S[sb + 3] = acc[r].w;
    }
    __syncthreads();
    // store: 64B runs (c2 lane-consecutive), both tgl halves
    int tid = t & 255, tgl = t >> 8;
    int c3 = tid >> 4, c2v = tid & 15;
    int tg = 2 * b + tgl;
    int base = c3 * 65536 + (tg >> 4) * 256 + (tg & 15) * 16 + c2v;
#pragma unroll
    for (int v = 0; v < 16; ++v)
      cohstore1(&psi[base + v * 4096], S[tgl * 4112 + c2v * 257 + c3 * 16 + v]);
  }
  gridbar(cnt, ++gen);

  // ===================== gate loop: 5 x (P1, P2) ===========================
  float g[16];
#pragma unroll
  for (int i = 0; i < 16; ++i) g[i] = gate[i];
  float* s = sm;

  for (int it = 0; it < 5; ++it) {
    // ---- P1: G2_01, G2_12, M16_0, M16_1. slab = low 12 bits, o = b -------
    {
      int f0 = t * 4, f1 = (512 + t) * 4;
      v4f a, c;
      cohload2(psi + b * 4096 + f0, psi + b * 4096 + f1, a, c);
      *(v4f*)(s + PAD(f0)) = a;
      *(v4f*)(s + PAD(f1)) = c;
    }
    __syncthreads();
    bondpair<8, 4, 0>(s, g, t);
    __syncthreads();
    bondpair<9, 5, 1>(s, g, t);
    __syncthreads();
    bondpair<10, 6, 2>(s, g, t);
    __syncthreads();
    bondpair<11, 7, 3>(s, g, t);
    __syncthreads();
    if (t < 256) vxf<256>(s, g, t);                          // M16_0
    __syncthreads();
    if (t < 256) vxf<16>(s, g, ((t >> 4) << 8) | (t & 15));  // M16_1
    __syncthreads();
    {
      int f0 = t * 4, f1 = (512 + t) * 4;
      cohstore(psi + b * 4096 + f0, *(const v4f*)(s + PAD(f0)));
      cohstore(psi + b * 4096 + f1, *(const v4f*)(s + PAD(f1)));
    }
    gridbar(cnt, ++gen);

    // ---- P2: G2_23, G2_34, M16_2..4. slab = bits {19..12,3..0}, o = b ----
    {
      int f0 = t * 4, f1 = (512 + t) * 4;
      int a0 = (f0 >> 8) * 65536 + ((f0 >> 4) & 15) * 4096 + b * 16 + (f0 & 15);
      int a1 = (f1 >> 8) * 65536 + ((f1 >> 4) & 15) * 4096 + b * 16 + (f1 & 15);
      v4f a, c;
      cohload2(psi + a0, psi + a1, a, c);
      *(v4f*)(s + PAD(f0)) = a;
      *(v4f*)(s + PAD(f1)) = c;
    }
    __syncthreads();
    bondpair<0, 8, 4>(s, g, t);
    __syncthreads();
    bondpair<1, 9, 5>(s, g, t);
    __syncthreads();
    bondpair<2, 10, 6>(s, g, t);
    __syncthreads();
    bondpair<3, 11, 7>(s, g, t);
    __syncthreads();
    if (t < 256) vxf<1>(s, g, t * 16);                       // M16_2
    __syncthreads();
    if (t < 256) vxf<256>(s, g, t);                          // M16_3
    __syncthreads();
    if (t < 256) vxf<16>(s, g, ((t >> 4) << 8) | (t & 15));  // M16_4
    __syncthreads();
    if (it == 4) {
      if (t < 64) {
        int idx = 0;
#pragma unroll
        for (int q = 0; q < 20; ++q) {
          int i = q / 5, j = q % 5;
          int pos = (j == 0) ? (11 - i)
                   : (j == 1) ? (7 - i)
                   : (j == 2) ? (3 - i)
                   : (j == 3) ? (19 - i)
                              : (15 - i);
          idx |= x[t * 20 + q] << pos;
        }
        if (((idx >> 4) & 255) == b) {
          int local = ((idx >> 16) & 15) * 256 + ((idx >> 12) & 15) * 16 +
                      (idx & 15);
          out[t] = s[PAD(local)];
        }
      }
    } else {
      int f0 = t * 4, f1 = (512 + t) * 4;
      int a0 = (f0 >> 8) * 65536 + ((f0 >> 4) & 15) * 4096 + b * 16 + (f0 & 15);
      int a1 = (f1 >> 8) * 65536 + ((f1 >> 4) & 15) * 4096 + b * 16 + (f1 & 15);
      cohstore(psi + a0, *(const v4f*)(s + PAD(f0)));
      cohstore(psi + a1, *(const v4f*)(s + PAD(f1)));
      gridbar(cnt, ++gen);
    }
  }
}

// ---------------------------------------------------------------------------
extern "C" void kernel_launch(void* const* d_in, const int* in_sizes, int n_in,
                              void* d_out, int out_size, void* d_ws, size_t ws_size,
                              hipStream_t stream) {
  const int* x = (const int*)d_in[0];
  const float* peps = (const float*)d_in[1];
  const float* gate = (const float*)d_in[2];
  float* ws = (float*)d_ws;
  float* out = (float*)d_out;
  int* cnt = (int*)(ws + CNTO);

  // zero the barrier tree (graph-capturable async memset node)
  hipMemsetAsync((void*)cnt, 0, 1088 * sizeof(int), stream);

  k_all<<<256, 512, 0, stream>>>(peps, x, gate, ws, out, cnt);
}

// Round 9
// 206.718 us; speedup vs baseline: 1.0299x; 1.0299x over previous
//
#include <hip/hip_runtime.h>

// ---------------------------------------------------------------------------
// PEPS 4x5, D=4, P=2, depth-5 gate sweeps, 64-point gather.
// ONE persistent kernel (plain launch), 13 fence-free tree barriers:
//   P1 cols -> P2 {M34T || M01} -> P3 t012 -> P4 psi0 -> 5x(G-P1, G-P2).
//
// COHERENCE (r6 lesson): every ws access is coherent (sc0 sc1 asm stores;
// sc0 sc1 asm x4 loads or __hip_atomic_load AGENT). Cached reads only for
// true inputs (peps/x/gate). Barriers need no wbl2/inv fences.
//
// r9 (r8 post-mortem): setup is parallelism-bound, not BW-bound. All setup
// phases now use the FULL 256-block grid AND minimal traffic:
//   M01:  256 blk = (c1, col-stripe16), col1 read once, LDS col-major dots.
//   t012: 256 blk = (c2, rowtile64, colquarter64), A in LDS, col2 16MB.
//   psi0: 256 blk = (tgquad, colquarter64), A in LDS, m34t 16MB,
//         S[64][68] LDS retranspose (aliases A) for 64B-run stores.
// coh_gemm2: 8+8 double-buffered dwordx4, vmcnt(8)+sched_barrier (rule #18).
// Gate layout: psi idx = c3<<16 | c4<<12 | c0<<8 | c1<<4 | c2.
// ---------------------------------------------------------------------------

#define PAD(i) ((i) + (((i) >> 4) << 2))   // +4 floats per 16 -> LDS bank spread
#define PIDX(i,j,p,u,d,l,r) (((((((i)*5+(j))*2+(p))*4+(u))*4+(d))*4+(l))*4+(r))

typedef float v4f __attribute__((ext_vector_type(4)));

// workspace float offsets
static constexpr int COL0  = 0;                    // [16][256]
static constexpr int COL1  = 4096;                 // [16][256][256]
static constexpr int COL2  = COL1 + 1048576;
static constexpr int COL3  = COL2 + 1048576;
static constexpr int COL4  = COL3 + 1048576;       // [16][256]
static constexpr int M01TO = COL4 + 4096;          // [c01=256][R2=256]
static constexpr int M34TO = M01TO + 65536;        // [L3=256][c34=256]
static constexpr int T12TO = M34TO + 65536;        // [c2=16][c01=256][R3=256]
static constexpr int PSIO  = T12TO + 1048576;      // [2^20] gate layout
static constexpr int CNTO  = PSIO + 1048576;       // barrier tree: 1088 ints

// ---------------- coherent-point access ------------------------------------
__device__ __forceinline__ float agl(const float* p) {      // coherent load
  return __hip_atomic_load(p, __ATOMIC_RELAXED, __HIP_MEMORY_SCOPE_AGENT);
}
__device__ __forceinline__ void cohload1(const float* p, v4f& a) {  // no wait!
  asm volatile("global_load_dwordx4 %0, %1, off sc0 sc1"
               : "=&v"(a) : "v"(p) : "memory");
}
__device__ __forceinline__ void cohload2(const float* p0, const float* p1,
                                         v4f& a, v4f& b) {
  asm volatile(
      "global_load_dwordx4 %0, %2, off sc0 sc1\n\t"
      "global_load_dwordx4 %1, %3, off sc0 sc1\n\t"
      "s_waitcnt vmcnt(0)"
      : "=&v"(a), "=&v"(b)
      : "v"(p0), "v"(p1)
      : "memory");
}
__device__ __forceinline__ void cohstore(float* p, v4f v) {
  asm volatile("global_store_dwordx4 %0, %1, off sc0 sc1"
               :
               : "v"(p), "v"(v)
               : "memory");
}
__device__ __forceinline__ void cohstore1(float* p, float v) {
  asm volatile("global_store_dword %0, %1, off sc0 sc1"
               :
               : "v"(p), "v"(v)
               : "memory");
}
__device__ __forceinline__ void vmdrain() {
  asm volatile("s_waitcnt vmcnt(0)" ::: "memory");
}
// waits with rule-#18 fence (register-only FMA must not hoist past the wait)
__device__ __forceinline__ void vmw8() {
  asm volatile("s_waitcnt vmcnt(8)" ::: "memory");
  __builtin_amdgcn_sched_barrier(0);
}
__device__ __forceinline__ void vmw0() {
  asm volatile("s_waitcnt vmcnt(0)" ::: "memory");
  __builtin_amdgcn_sched_barrier(0);
}

// ---------------- two-level fence-free grid barrier ------------------------
__device__ __forceinline__ void gridbar(int* cnts, int gen) {
  vmdrain();        // asm stores untracked by compiler: drain manually
  __syncthreads();  // all waves' stores completed at coherent point
  if (threadIdx.x == 0) {
    int* gc = cnts + (blockIdx.x >> 4) * 64;
    int* root = cnts + 1024;
    int prev = __hip_atomic_fetch_add(gc, 1, __ATOMIC_RELAXED,
                                      __HIP_MEMORY_SCOPE_AGENT);
    if ((prev & 15) == 15)
      __hip_atomic_fetch_add(root, 1, __ATOMIC_RELAXED,
                             __HIP_MEMORY_SCOPE_AGENT);
    while (__hip_atomic_load(root, __ATOMIC_RELAXED,
                             __HIP_MEMORY_SCOPE_AGENT) < gen * 16) {
      __builtin_amdgcn_s_sleep(2);
    }
  }
  __syncthreads();
}

// ---------------- pipelined coherent GEMM inner loop (2 rows x 4 cols) -----
// acc{0,1} += sum_R Ar{0,1}[R] * B[R][4 cols]; Bb = &B[0][col4] (row
// stride 256, coherent global); Ar0/Ar1 = LDS row pointers (pad-260 rows).
__device__ __forceinline__ void coh_gemm2(const float* Bb, const float* Ar0,
                                          const float* Ar1, v4f& acc0,
                                          v4f& acc1) {
  v4f pa0, pa1, pa2, pa3, pa4, pa5, pa6, pa7;
  v4f pb0, pb1, pb2, pb3, pb4, pb5, pb6, pb7;
#define ISSUE8(buf, base)                                                      \
  cohload1(Bb + ((base) + 0) * 256, buf##0);                                   \
  cohload1(Bb + ((base) + 1) * 256, buf##1);                                   \
  cohload1(Bb + ((base) + 2) * 256, buf##2);                                   \
  cohload1(Bb + ((base) + 3) * 256, buf##3);                                   \
  cohload1(Bb + ((base) + 4) * 256, buf##4);                                   \
  cohload1(Bb + ((base) + 5) * 256, buf##5);                                   \
  cohload1(Bb + ((base) + 6) * 256, buf##6);                                   \
  cohload1(Bb + ((base) + 7) * 256, buf##7)
#define FMA8(buf, base)                                                        \
  {                                                                            \
    v4f A0a = *(const v4f*)&Ar0[(base)];                                       \
    v4f A0b = *(const v4f*)&Ar0[(base) + 4];                                   \
    v4f A1a = *(const v4f*)&Ar1[(base)];                                       \
    v4f A1b = *(const v4f*)&Ar1[(base) + 4];                                   \
    acc0 += buf##0 * A0a.x;  acc1 += buf##0 * A1a.x;                           \
    acc0 += buf##1 * A0a.y;  acc1 += buf##1 * A1a.y;                           \
    acc0 += buf##2 * A0a.z;  acc1 += buf##2 * A1a.z;                           \
    acc0 += buf##3 * A0a.w;  acc1 += buf##3 * A1a.w;                           \
    acc0 += buf##4 * A0b.x;  acc1 += buf##4 * A1b.x;                           \
    acc0 += buf##5 * A0b.y;  acc1 += buf##5 * A1b.y;                           \
    acc0 += buf##6 * A0b.z;  acc1 += buf##6 * A1b.z;                           \
    acc0 += buf##7 * A0b.w;  acc1 += buf##7 * A1b.w;                           \
  }
  ISSUE8(pa, 0);
#pragma unroll
  for (int cp = 0; cp < 16; ++cp) {
    ISSUE8(pb, cp * 16 + 8);
    vmw8();                       // pa ready (8 pb outstanding)
    FMA8(pa, cp * 16);
    if (cp < 15) {
      ISSUE8(pa, cp * 16 + 16);
      vmw8();                     // pb ready (8 pa outstanding)
    } else {
      vmw0();
    }
    FMA8(pb, cp * 16 + 8);
  }
#undef ISSUE8
#undef FMA8
}

// ---------------- register-level 2-qubit gate ------------------------------
template <int NB, int HI, int LO>
__device__ __forceinline__ void gate2(float* x, const float* __restrict__ g) {
  constexpr int H = 1 << HI, L = 1 << LO, N = 1 << NB;
#pragma unroll
  for (int o = 0; o < N; ++o) {
    if (o & (H | L)) continue;
    float v0 = x[o], v1 = x[o + L], v2 = x[o + H], v3 = x[o + H + L];
    x[o]         = g[0]  * v0 + g[1]  * v1 + g[2]  * v2 + g[3]  * v3;
    x[o + L]     = g[4]  * v0 + g[5]  * v1 + g[6]  * v2 + g[7]  * v3;
    x[o + H]     = g[8]  * v0 + g[9]  * v1 + g[10] * v2 + g[11] * v3;
    x[o + H + L] = g[12] * v0 + g[13] * v1 + g[14] * v2 + g[15] * v3;
  }
}

template <int ST>
__device__ __forceinline__ void vxf(float* s, const float* __restrict__ g, int b) {
  float x[16];
#pragma unroll
  for (int m = 0; m < 16; ++m) x[m] = s[PAD(b + m * ST)];
  gate2<4, 3, 2>(x, g);
  gate2<4, 2, 1>(x, g);
  gate2<4, 1, 0>(x, g);
#pragma unroll
  for (int m = 0; m < 16; ++m) s[PAD(b + m * ST)] = x[m];
}

template <int B2, int B1, int B0>
__device__ __forceinline__ void bondpair(float* s, const float* __restrict__ g,
                                         int t) {
  constexpr int MASK = (1 << B2) | (1 << B1) | (1 << B0);
  int b = 0, rem = t;
#pragma unroll
  for (int p = 0; p < 12; ++p) {
    if (!((MASK >> p) & 1)) {
      b |= (rem & 1) << p;
      rem >>= 1;
    }
  }
  float x[8];
#pragma unroll
  for (int m = 0; m < 8; ++m) {
    int off = ((m >> 2) & 1) * (1 << B2) + ((m >> 1) & 1) * (1 << B1) +
              (m & 1) * (1 << B0);
    x[m] = s[PAD(b + off)];
  }
  gate2<3, 2, 1>(x, g);  // bond (B2, B1)
  gate2<3, 1, 0>(x, g);  // bond (B1, B0)
#pragma unroll
  for (int m = 0; m < 8; ++m) {
    int off = ((m >> 2) & 1) * (1 << B2) + ((m >> 1) & 1) * (1 << B1) +
              (m & 1) * (1 << B0);
    s[PAD(b + off)] = x[m];
  }
}

// ---------------------------------------------------------------------------
// Grid 256 x 512, plain launch. LDS 16640 floats (66.6KB) -> 1+ block/CU.
// ---------------------------------------------------------------------------
__global__ __launch_bounds__(512) void k_all(const float* __restrict__ peps,
                                             const int* __restrict__ x,
                                             const float* __restrict__ gate,
                                             float* __restrict__ ws,
                                             float* __restrict__ out,
                                             int* __restrict__ cnt) {
  __shared__ float sm[16640];
  const int t = threadIdx.x;   // 0..511
  const int b = blockIdx.x;    // 0..255
  float* psi = ws + PSIO;
  int gen = 0;

  // ===================== phase 1: column tensors ===========================
  if (b < 192) {
    float* p01 = sm;
    float* p23 = sm + 4096;
    int col = 1 + (b >> 6);
    int pb = b & 63;
#pragma unroll
    for (int k = 0; k < 8; ++k) {
      int e = k * 512 + t;
      int r12 = e & 15, l12 = (e >> 4) & 15, d2 = (e >> 8) & 3, p = e >> 10;
      int l1 = l12 >> 2, l2 = l12 & 3, r1 = r12 >> 2, r2 = r12 & 3;
      float s01 = 0.f, s23 = 0.f;
#pragma unroll
      for (int d = 0; d < 4; ++d) {
        s01 += peps[PIDX(0, col, (p >> 1), 0, d, l1, r1)] *
               peps[PIDX(1, col, (p & 1), d, d2, l2, r2)];
        s23 += peps[PIDX(2, col, (p >> 1), d2, d, l1, r1)] *
               peps[PIDX(3, col, (p & 1), d, 0, l2, r2)];
      }
      p01[e] = s01;
      p23[e] = s23;
    }
    __syncthreads();
    const int coloffs[3] = {COL1, COL2, COL3};
    float* outc = ws + coloffs[col - 1];
#pragma unroll
    for (int pp = 0; pp < 2; ++pp) {
      int part = pb * 2 + pp;
#pragma unroll
      for (int k = 0; k < 4; ++k) {
        int eq = part * 8192 + (k * 512 + t) * 4;
        int r34b = eq & 15;
        int r12 = (eq >> 4) & 15, l34 = (eq >> 8) & 15, l12 = (eq >> 12) & 15;
        int p = eq >> 16;
        int pa = p >> 2, pbv = p & 3;
        v4f acc = {0.f, 0.f, 0.f, 0.f};
#pragma unroll
        for (int d2 = 0; d2 < 4; ++d2) {
          float a01 = p01[((((pa * 4 + d2) << 4) | l12) << 4) | r12];
          const float4 b4 =
              *(const float4*)&p23[((((pbv * 4 + d2) << 4) | l34) << 4) | r34b];
          acc.x += a01 * b4.x;
          acc.y += a01 * b4.y;
          acc.z += a01 * b4.z;
          acc.w += a01 * b4.w;
        }
        cohstore(&outc[eq], acc);
      }
    }
  } else if (b < 194) {
    float* p01 = sm;
    float* p23 = sm + 4096;
    int col = (b == 192) ? 0 : 4;
    const int lsh = (col == 0) ? 0 : 2;
    const int rsh = (col == 4) ? 0 : 2;
    const int ldim = 1 << lsh, rdim = 1 << rsh;
    const int LLB = 2 * lsh, RRB = 2 * rsh;
    const int LL = 1 << LLB, RR = 1 << RRB;
    int n12 = (LL * RR) << 4;
    for (int e = t; e < n12; e += 512) {
      int r12 = e & (RR - 1);
      int l12 = (e >> RRB) & (LL - 1);
      int d2 = (e >> (RRB + LLB)) & 3;
      int p = e >> (RRB + LLB + 2);
      int l1 = l12 >> lsh, l2 = l12 & (ldim - 1);
      int r1 = r12 >> rsh, r2 = r12 & (rdim - 1);
      float s01 = 0.f, s23 = 0.f;
      for (int d = 0; d < 4; ++d) {
        s01 += peps[PIDX(0, col, (p >> 1), 0, d, l1, r1)] *
               peps[PIDX(1, col, (p & 1), d, d2, l2, r2)];
        s23 += peps[PIDX(2, col, (p >> 1), d2, d, l1, r1)] *
               peps[PIDX(3, col, (p & 1), d, 0, l2, r2)];
      }
      p01[e] = s01;
      p23[e] = s23;
    }
    __syncthreads();
    const int LB = 2 * LLB, RB = 2 * RRB;
    int total = 16 << (LB + RB);
    float* outc = ws + ((col == 0) ? COL0 : COL4);
    for (int e = t; e < total; e += 512) {
      int r = e & ((1 << RB) - 1);
      int l = (e >> RB) & ((1 << LB) - 1);
      int p = e >> (RB + LB);
      int r34 = r & (RR - 1), r12 = r >> RRB;
      int l34 = l & (LL - 1), l12 = l >> LLB;
      int pa = p >> 2, pbv = p & 3;
      float sacc = 0.f;
      for (int d2 = 0; d2 < 4; ++d2) {
        sacc += p01[((((pa * 4 + d2) << LLB) | l12) << RRB) | r12] *
                p23[((((pbv * 4 + d2) << LLB) | l34) << RRB) | r34];
      }
      cohstore1(&outc[e], sacc);
    }
  }
  gridbar(cnt, ++gen);

  // ==== phase 2: M34T (t<256, blk=L3)  ||  M01 (t>=256, blk=(c1,stripe)) ===
  {
    float* c3buf = sm;            // [4112]
    float* c4buf = sm + 4112;     // [4112]
    float* col0l = sm + 8224;     // [16][260] col-major-K
    float* s1c   = sm + 12384;    // [16 cols][260 K]
    const float* col3 = ws + COL3;
    const float* col4 = ws + COL4;
    const int L3 = b;
    const int c1 = b >> 4, q = b & 15;
    if (t < 256) {
      float v3[16], v4[16];
#pragma unroll
      for (int k = 0; k < 16; ++k) {
        v4[k] = agl(&col4[k * 256 + t]);
        v3[k] = agl(&col3[k * 65536 + L3 * 256 + t]);
      }
#pragma unroll
      for (int k = 0; k < 16; ++k) {
        c4buf[k * 257 + t] = v4[k];
        c3buf[k * 257 + t] = v3[k];
      }
    } else {
      int tt = t - 256;
      const float* col0g = ws + COL0;
#pragma unroll
      for (int k = 0; k < 16; ++k)
        col0l[k * 260 + tt] = agl(&col0g[k * 256 + tt]);
      // stage col1[c1][R1=tt][stripe q] -> s1c[col][K], col-major
      const float* c1p = ws + COL1 + c1 * 65536 + tt * 256 + q * 16;
      v4f w0, w1, w2, w3;
      cohload1(c1p + 0, w0);
      cohload1(c1p + 4, w1);
      cohload1(c1p + 8, w2);
      cohload1(c1p + 12, w3);
      vmw0();
#pragma unroll
      for (int j = 0; j < 4; ++j) s1c[(0 * 4 + j) * 260 + tt] = w0[j];
#pragma unroll
      for (int j = 0; j < 4; ++j) s1c[(1 * 4 + j) * 260 + tt] = w1[j];
#pragma unroll
      for (int j = 0; j < 4; ++j) s1c[(2 * 4 + j) * 260 + tt] = w2[j];
#pragma unroll
      for (int j = 0; j < 4; ++j) s1c[(3 * 4 + j) * 260 + tt] = w3[j];
    }
    __syncthreads();
    if (t < 256) {
      int c3 = t >> 4, c4 = t & 15;
      float acc = 0.f;
      for (int B = 0; B < 256; ++B)
        acc += c3buf[c3 * 257 + B] * c4buf[c4 * 257 + B];
      cohstore1(&(ws + M34TO)[L3 * 256 + t], acc);
    } else {
      int tt = t - 256;
      int c0 = tt >> 4, rc = tt & 15;
      float acc = 0.f;
#pragma unroll
      for (int R = 0; R < 256; R += 4) {
        v4f a4 = *(const v4f*)&col0l[c0 * 260 + R];
        v4f s4 = *(const v4f*)&s1c[rc * 260 + R];
        acc += a4.x * s4.x + a4.y * s4.y + a4.z * s4.z + a4.w * s4.w;
      }
      cohstore1(&(ws + M01TO)[(c0 * 16 + c1) * 256 + q * 16 + rc], acc);
    }
  }
  gridbar(cnt, ++gen);

  // == phase 3: T012 = M01 x Col2. 256 blk = (c2, rowtile64, colquarter64) ==
  {
    float* A = sm;  // [64 rows][260]
    int c2 = b >> 4, tile = (b >> 2) & 3, qr = b & 3;
    const float* src = ws + M01TO + tile * 16384;
    {
      v4f v0, v1, v2, v3, v4, v5, v6, v7;
      cohload1(src + (0 * 512 + t) * 4, v0);
      cohload1(src + (1 * 512 + t) * 4, v1);
      cohload1(src + (2 * 512 + t) * 4, v2);
      cohload1(src + (3 * 512 + t) * 4, v3);
      cohload1(src + (4 * 512 + t) * 4, v4);
      cohload1(src + (5 * 512 + t) * 4, v5);
      cohload1(src + (6 * 512 + t) * 4, v6);
      cohload1(src + (7 * 512 + t) * 4, v7);
      vmw0();
#define PUT(k, vv)                                                             \
  {                                                                            \
    int f = (k * 512 + t) * 4;                                                 \
    *(v4f*)&A[(f >> 8) * 260 + (f & 255)] = vv;                                \
  }
      PUT(0, v0) PUT(1, v1) PUT(2, v2) PUT(3, v3)
      PUT(4, v4) PUT(5, v5) PUT(6, v6) PUT(7, v7)
#undef PUT
    }
    __syncthreads();
    int cg = t & 15, rg = t >> 4;
    v4f acc0 = {0.f, 0.f, 0.f, 0.f}, acc1 = {0.f, 0.f, 0.f, 0.f};
    coh_gemm2(ws + COL2 + c2 * 65536 + qr * 64 + cg * 4, &A[(rg * 2) * 260],
              &A[(rg * 2 + 1) * 260], acc0, acc1);
    float* t012p = ws + T12TO;
    int row0 = tile * 64 + rg * 2;
    cohstore(&t012p[c2 * 65536 + row0 * 256 + qr * 64 + cg * 4], acc0);
    cohstore(&t012p[c2 * 65536 + (row0 + 1) * 256 + qr * 64 + cg * 4], acc1);
  }
  gridbar(cnt, ++gen);

  // == phase 4: psi = T012 x M34T (gate layout). 256 blk = (tgquad, cq64) ===
  {
    float* A = sm;  // [64 rows=(tgi,c2)][260]
    int tgq = b >> 2, cq = b & 3;
    const float* t012p = ws + T12TO;
    {
      v4f v0, v1, v2, v3, v4, v5, v6, v7;
#define SRC(k)                                                                 \
  (t012p + (((k * 512 + t) * 4 >> 8) & 15) * 65536 +                           \
   (tgq * 4 + ((k * 512 + t) * 4 >> 12)) * 256 + ((k * 512 + t) * 4 & 255))
      cohload1(SRC(0), v0);
      cohload1(SRC(1), v1);
      cohload1(SRC(2), v2);
      cohload1(SRC(3), v3);
      cohload1(SRC(4), v4);
      cohload1(SRC(5), v5);
      cohload1(SRC(6), v6);
      cohload1(SRC(7), v7);
#undef SRC
      vmw0();
#define PUT(k, vv)                                                             \
  {                                                                            \
    int f = (k * 512 + t) * 4;                                                 \
    *(v4f*)&A[(f >> 8) * 260 + (f & 255)] = vv;                                \
  }
      PUT(0, v0) PUT(1, v1) PUT(2, v2) PUT(3, v3)
      PUT(4, v4) PUT(5, v5) PUT(6, v6) PUT(7, v7)
#undef PUT
    }
    __syncthreads();
    int cg = t & 15, rg = t >> 4;
    v4f acc0 = {0.f, 0.f, 0.f, 0.f}, acc1 = {0.f, 0.f, 0.f, 0.f};
    coh_gemm2(ws + M34TO + cq * 64 + cg * 4, &A[(rg * 2) * 260],
              &A[(rg * 2 + 1) * 260], acc0, acc1);
    __syncthreads();  // all gemm LDS reads done; reuse A region as S[64][68]
    float* S = sm;
    *(v4f*)&S[(rg * 2 + 0) * 68 + cg * 4] = acc0;
    *(v4f*)&S[(rg * 2 + 1) * 68 + cg * 4] = acc1;
    __syncthreads();
#pragma unroll
    for (int k = 0; k < 2; ++k) {
      int idx = k * 512 + t;
      int c2g = idx & 3, c4 = (idx >> 2) & 15, c3l = (idx >> 6) & 3;
      int tgi = (idx >> 8) & 3;
      int tg = tgq * 4 + tgi;
      int col = c3l * 16 + c4;
      v4f v;
      v.x = S[(tgi * 16 + c2g * 4 + 0) * 68 + col];
      v.y = S[(tgi * 16 + c2g * 4 + 1) * 68 + col];
      v.z = S[(tgi * 16 + c2g * 4 + 2) * 68 + col];
      v.w = S[(tgi * 16 + c2g * 4 + 3) * 68 + col];
      int addr = (cq * 4 + c3l) * 65536 + c4 * 4096 + (tg >> 4) * 256 +
                 (tg & 15) * 16 + c2g * 4;
      cohstore(&psi[addr], v);
    }
  }
  gridbar(cnt, ++gen);

  // ===================== gate loop: 5 x (P1, P2) ===========================
  float g[16];
#pragma unroll
  for (int i = 0; i < 16; ++i) g[i] = gate[i];
  float* s = sm;

  for (int it = 0; it < 5; ++it) {
    // ---- P1: G2_01, G2_12, M16_0, M16_1. slab = low 12 bits, o = b -------
    {
      int f0 = t * 4, f1 = (512 + t) * 4;
      v4f a, c;
      cohload2(psi + b * 4096 + f0, psi + b * 4096 + f1, a, c);
      *(v4f*)(s + PAD(f0)) = a;
      *(v4f*)(s + PAD(f1)) = c;
    }
    __syncthreads();
    bondpair<8, 4, 0>(s, g, t);
    __syncthreads();
    bondpair<9, 5, 1>(s, g, t);
    __syncthreads();
    bondpair<10, 6, 2>(s, g, t);
    __syncthreads();
    bondpair<11, 7, 3>(s, g, t);
    __syncthreads();
    if (t < 256) vxf<256>(s, g, t);                          // M16_0
    __syncthreads();
    if (t < 256) vxf<16>(s, g, ((t >> 4) << 8) | (t & 15));  // M16_1
    __syncthreads();
    {
      int f0 = t * 4, f1 = (512 + t) * 4;
      cohstore(psi + b * 4096 + f0, *(const v4f*)(s + PAD(f0)));
      cohstore(psi + b * 4096 + f1, *(const v4f*)(s + PAD(f1)));
    }
    gridbar(cnt, ++gen);

    // ---- P2: G2_23, G2_34, M16_2..4. slab = bits {19..12,3..0}, o = b ----
    {
      int f0 = t * 4, f1 = (512 + t) * 4;
      int a0 = (f0 >> 8) * 65536 + ((f0 >> 4) & 15) * 4096 + b * 16 + (f0 & 15);
      int a1 = (f1 >> 8) * 65536 + ((f1 >> 4) & 15) * 4096 + b * 16 + (f1 & 15);
      v4f a, c;
      cohload2(psi + a0, psi + a1, a, c);
      *(v4f*)(s + PAD(f0)) = a;
      *(v4f*)(s + PAD(f1)) = c;
    }
    __syncthreads();
    bondpair<0, 8, 4>(s, g, t);
    __syncthreads();
    bondpair<1, 9, 5>(s, g, t);
    __syncthreads();
    bondpair<2, 10, 6>(s, g, t);
    __syncthreads();
    bondpair<3, 11, 7>(s, g, t);
    __syncthreads();
    if (t < 256) vxf<1>(s, g, t * 16);                       // M16_2
    __syncthreads();
    if (t < 256) vxf<256>(s, g, t);                          // M16_3
    __syncthreads();
    if (t < 256) vxf<16>(s, g, ((t >> 4) << 8) | (t & 15));  // M16_4
    __syncthreads();
    if (it == 4) {
      if (t < 64) {
        int idx = 0;
#pragma unroll
        for (int q = 0; q < 20; ++q) {
          int i = q / 5, j = q % 5;
          int pos = (j == 0) ? (11 - i)
                   : (j == 1) ? (7 - i)
                   : (j == 2) ? (3 - i)
                   : (j == 3) ? (19 - i)
                              : (15 - i);
          idx |= x[t * 20 + q] << pos;
        }
        if (((idx >> 4) & 255) == b) {
          int local = ((idx >> 16) & 15) * 256 + ((idx >> 12) & 15) * 16 +
                      (idx & 15);
          out[t] = s[PAD(local)];
        }
      }
    } else {
      int f0 = t * 4, f1 = (512 + t) * 4;
      int a0 = (f0 >> 8) * 65536 + ((f0 >> 4) & 15) * 4096 + b * 16 + (f0 & 15);
      int a1 = (f1 >> 8) * 65536 + ((f1 >> 4) & 15) * 4096 + b * 16 + (f1 & 15);
      cohstore(psi + a0, *(const v4f*)(s + PAD(f0)));
      cohstore(psi + a1, *(const v4f*)(s + PAD(f1)));
      gridbar(cnt, ++gen);
    }
  }
}

// ---------------------------------------------------------------------------
extern "C" void kernel_launch(void* const* d_in, const int* in_sizes, int n_in,
                              void* d_out, int out_size, void* d_ws, size_t ws_size,
                              hipStream_t stream) {
  const int* x = (const int*)d_in[0];
  const float* peps = (const float*)d_in[1];
  const float* gate = (const float*)d_in[2];
  float* ws = (float*)d_ws;
  float* out = (float*)d_out;
  int* cnt = (int*)(ws + CNTO);

  // zero the barrier tree (graph-capturable async memset node)
  hipMemsetAsync((void*)cnt, 0, 1088 * sizeof(int), stream);

  k_all<<<256, 512, 0, stream>>>(peps, x, gate, ws, out, cnt);
}